// Round 4
// baseline (523.462 us; speedup 1.0000x reference)
//
#include <hip/hip_runtime.h>
#include <hip/hip_bf16.h>
#include <math.h>

#define D_IN   256
#define D_OUT  128
#define DZ     384   // three planar arrays Zl|Zh|Zm, each N x 128 bf16

typedef __attribute__((ext_vector_type(8))) short short8;
typedef __attribute__((ext_vector_type(4))) float floatx4;
typedef __attribute__((ext_vector_type(4))) unsigned uintx4;

__device__ __forceinline__ unsigned short f2bf(float f) {
  union { float f; unsigned u; } v; v.f = f;
  unsigned r = v.u + 0x7fffu + ((v.u >> 16) & 1u);  // RNE
  return (unsigned short)(r >> 16);
}

// ---------------------------------------------------------------------------
// K0: pack [Wl|Wh|Wm] into MFMA B-fragment order.
// frag f = kt*24+nt holds B[k=kt*32+quad*8+j][n=nt*16+(lane&15)]
// flat index t = f*512 + lane*8 + j.
// ---------------------------------------------------------------------------
__global__ void repack_w_kernel(const float* __restrict__ Wl,
                                const float* __restrict__ Wh,
                                const float* __restrict__ Wm,
                                unsigned short* __restrict__ Bpack) {
  int t = blockIdx.x * 256 + threadIdx.x;  // 0..98303
  int j = t & 7;
  int lane = (t >> 3) & 63;
  int f = t >> 9;          // 0..191
  int nt = f % 24, kt = f / 24;
  int k = kt * 32 + (lane >> 4) * 8 + j;
  int n = nt * 16 + (lane & 15);
  const float* W = (n < 128) ? Wl : (n < 256 ? Wh : Wm);
  Bpack[t] = f2bf(W[k * D_OUT + (n & 127)]);
}

// ---------------------------------------------------------------------------
// K0b: x (fp32) -> xb (bf16), 8 elems/thread, 16B stores.
// ---------------------------------------------------------------------------
__global__ void xcvt_kernel(const float* __restrict__ x,
                            unsigned short* __restrict__ xb, int n8) {
  int i = blockIdx.x * 256 + threadIdx.x;
  if (i < n8) {
    const float4* p = (const float4*)x + (size_t)i * 2;
    float4 f0 = p[0], f1 = p[1];
    short8 o;
    o[0] = (short)f2bf(f0.x); o[1] = (short)f2bf(f0.y);
    o[2] = (short)f2bf(f0.z); o[3] = (short)f2bf(f0.w);
    o[4] = (short)f2bf(f1.x); o[5] = (short)f2bf(f1.y);
    o[6] = (short)f2bf(f1.z); o[7] = (short)f2bf(f1.w);
    ((short8*)xb)[i] = o;
  }
}

// ---------------------------------------------------------------------------
// K1: Z = xb @ [Wl|Wh|Wm], bf16 MFMA. 512-thr block = 8 waves over the same
// 64 rows; wave w owns ctiles w*3..w*3+2 (acc 4 strips x 3 ctiles = 48 AGPR).
// Epilogue writes PLANAR Zl|Zh|Zm (each n_nodes x 128 bf16) so that the
// node kernel's gather working set per pass is 25.6MB (fits aggregate L2).
// ---------------------------------------------------------------------------
#define LDSROW 392  // shorts/row: 784 B (16B-aligned); 4-row stride = 16 mod 32
__global__ __launch_bounds__(512, 4) void gemm_kernel(
    const unsigned short* __restrict__ xb,
    const unsigned short* __restrict__ Bpack, unsigned short* __restrict__ Z3,
    int n_nodes) {
  __shared__ unsigned short tile[64 * LDSROW];
  const int lane = threadIdx.x & 63;
  const int w = threadIdx.x >> 6;  // 0..7: column group (3 ctiles)
  const int rowbase = blockIdx.x * 64;
  const int m16 = lane & 15, quad = lane >> 4;

  floatx4 acc[4][3];
#pragma unroll
  for (int s = 0; s < 4; s++)
#pragma unroll
    for (int c = 0; c < 3; c++) acc[s][c] = (floatx4)(0.f);

  const short8* xr[4];
#pragma unroll
  for (int s = 0; s < 4; s++) {
    int r = rowbase + s * 16 + m16;
    if (r > n_nodes - 1) r = n_nodes - 1;  // clamp; stores are guarded
    xr[s] = (const short8*)xb + (size_t)r * 32 + quad;  // row*256/8 + quad
  }
  const short8* bp = (const short8*)Bpack + lane;

#pragma unroll
  for (int kt = 0; kt < 8; kt++) {
    short8 a[4];
#pragma unroll
    for (int s = 0; s < 4; s++) a[s] = xr[s][kt * 4];
#pragma unroll
    for (int c = 0; c < 3; c++) {
      short8 b = bp[(kt * 24 + w * 3 + c) * 64];
#pragma unroll
      for (int s = 0; s < 4; s++)
        acc[s][c] =
            __builtin_amdgcn_mfma_f32_16x16x32_bf16(a[s], b, acc[s][c], 0, 0, 0);
    }
  }

  // stage to LDS in C-layout (row = s*16+quad*4+r, col = (w*3+c)*16+m16)
#pragma unroll
  for (int s = 0; s < 4; s++)
#pragma unroll
    for (int c = 0; c < 3; c++)
#pragma unroll
      for (int r = 0; r < 4; r++)
        tile[(s * 16 + quad * 4 + r) * LDSROW + (w * 3 + c) * 16 + m16] =
            f2bf(acc[s][c][r]);
  __syncthreads();

  // coalesced store: 64 rows x 48 chunks of 16B -> planar [sel][row][128]
  const size_t zsh = (size_t)n_nodes * 128;  // shorts per plane
#pragma unroll
  for (int it = 0; it < 6; it++) {
    int chunk = it * 512 + threadIdx.x;
    int row = chunk / 48, c8 = chunk % 48;  // 16B chunk index 0..47
    int grow = rowbase + row;
    if (grow < n_nodes)
      *(short8*)(Z3 + (size_t)(c8 >> 4) * zsh + (size_t)grow * 128 +
                 (c8 & 15) * 8) = *(const short8*)&tile[row * LDSROW + c8 * 8];
  }
}

// ---------------------------------------------------------------------------
// CSR build, rank-based (single atomic pass):
//   rank_kernel: rank[e] = atomicAdd(cnt[dst],1)   (only atomics in pipeline)
//   scan1/2/3 : exclusive scan of cnt -> rowptr (+ rowptr[N]=E)
//   scatter   : meta[rowptr[dst]+rank[e]] = {src, bf16(wl)|bf16(wh)<<16}
// ---------------------------------------------------------------------------
__global__ void rank_kernel(const int* __restrict__ dst, int* __restrict__ cnt,
                            int* __restrict__ rank, int E) {
  int e = (blockIdx.x * 256 + threadIdx.x) * 4;
  if (e + 3 < E) {
    int4 d = *(const int4*)&dst[e];
    int r0 = atomicAdd(&cnt[d.x], 1);
    int r1 = atomicAdd(&cnt[d.y], 1);
    int r2 = atomicAdd(&cnt[d.z], 1);
    int r3 = atomicAdd(&cnt[d.w], 1);
    *(int4*)&rank[e] = make_int4(r0, r1, r2, r3);
  } else {
    for (int k = e; k < E; k++) rank[k] = atomicAdd(&cnt[dst[k]], 1);
  }
}

__global__ __launch_bounds__(256) void scan1_kernel(
    const int* __restrict__ cnt, int* __restrict__ rowptr,
    int* __restrict__ bsum, int n) {
  __shared__ int sd[256];
  int t = threadIdx.x;
  int base = blockIdx.x * 1024 + t * 4;
  int v0 = base + 0 < n ? cnt[base + 0] : 0;
  int v1 = base + 1 < n ? cnt[base + 1] : 0;
  int v2 = base + 2 < n ? cnt[base + 2] : 0;
  int v3 = base + 3 < n ? cnt[base + 3] : 0;
  int tsum = v0 + v1 + v2 + v3;
  sd[t] = tsum;
  __syncthreads();
  for (int off = 1; off < 256; off <<= 1) {
    int add = (t >= off) ? sd[t - off] : 0;
    __syncthreads();
    sd[t] += add;
    __syncthreads();
  }
  int excl = sd[t] - tsum;
  if (base + 0 < n) rowptr[base + 0] = excl;
  if (base + 1 < n) rowptr[base + 1] = excl + v0;
  if (base + 2 < n) rowptr[base + 2] = excl + v0 + v1;
  if (base + 3 < n) rowptr[base + 3] = excl + v0 + v1 + v2;
  if (t == 255) bsum[blockIdx.x] = sd[255];
}

__global__ __launch_bounds__(128) void scan2_kernel(int* __restrict__ bsum,
                                                    int nb) {
  __shared__ int sd[128];
  int t = threadIdx.x;
  int v = t < nb ? bsum[t] : 0;
  sd[t] = v;
  __syncthreads();
  for (int off = 1; off < 128; off <<= 1) {
    int add = (t >= off) ? sd[t - off] : 0;
    __syncthreads();
    sd[t] += add;
    __syncthreads();
  }
  if (t < nb) bsum[t] = sd[t] - v;  // exclusive
}

__global__ void scan3_kernel(int* __restrict__ rowptr,
                             const int* __restrict__ bsum, int n, int E) {
  int i = blockIdx.x * 256 + threadIdx.x;
  if (i < n) {
    rowptr[i] = rowptr[i] + bsum[i >> 10];
    if (i == 0) rowptr[n] = E;
  }
}

__global__ void scatter_kernel(const int* __restrict__ src,
                               const int* __restrict__ dst,
                               const float* __restrict__ wlo,
                               const float* __restrict__ whi,
                               const int* __restrict__ rowptr,
                               const int* __restrict__ rank,
                               uint2* __restrict__ meta, int E) {
  int e = blockIdx.x * 256 + threadIdx.x;
  if (e < E) {
    int d = dst[e];
    int pos = rowptr[d] + rank[e];
    unsigned wl = f2bf(wlo[e]), wh = f2bf(whi[e]);
    meta[pos] = make_uint2((unsigned)src[e], wl | (wh << 16));
  }
}

// ---------------------------------------------------------------------------
// K_node: CSR gather + relu + attention3, SPLIT-PASS over planar Zl then Zh.
// Per pass the gather working set is 25.6MB (3.2MB per home-XCD L2 slice),
// so random gathers become mostly L2 hits. Streams (meta, Zm, out) use
// non-temporal hints to avoid evicting the hot plane.
// Lane layout: 16 lanes per edge (256B row), 4 edges per wave-load:
//   g   = (lane>>4)&3   edge subgroup
//   d16 = lane&15       dim block: 8 dims d16*8..d16*8+7
// Group partials combined with shfl_xor(16/32) after each pass.
// ---------------------------------------------------------------------------
__device__ __forceinline__ void gpass(const char* __restrict__ Zb,
                                      const unsigned long long* __restrict__ meta,
                                      int start, int end, int g, unsigned zlane,
                                      int useHigh, floatx4& A, floatx4& B) {
  auto pick = [&](unsigned long long m) {
    unsigned p = (unsigned)(m >> 32);
    return __uint_as_float(useHigh ? (p & 0xffff0000u) : (p << 16));
  };
  auto step = [&](uint4 z, float wv) {
    A.x += wv * __uint_as_float(z.x << 16);
    A.y += wv * __uint_as_float(z.x & 0xffff0000u);
    A.z += wv * __uint_as_float(z.y << 16);
    A.w += wv * __uint_as_float(z.y & 0xffff0000u);
    B.x += wv * __uint_as_float(z.z << 16);
    B.y += wv * __uint_as_float(z.z & 0xffff0000u);
    B.z += wv * __uint_as_float(z.w << 16);
    B.w += wv * __uint_as_float(z.w & 0xffff0000u);
  };
  int j = start;
  const int nfull = (end - start) & ~7;
  for (; j < start + nfull; j += 8) {  // 8 edges = 2 quad-groups per iter
    unsigned long long m0 = __builtin_nontemporal_load(&meta[j + g]);
    unsigned long long m1 = __builtin_nontemporal_load(&meta[j + 4 + g]);
    uint4 z0 = *(const uint4*)(Zb + ((unsigned)(m0 & 0xffffffffu) * 256u + zlane));
    uint4 z1 = *(const uint4*)(Zb + ((unsigned)(m1 & 0xffffffffu) * 256u + zlane));
    step(z0, pick(m0));
    step(z1, pick(m1));
  }
  for (; j < end; j += 4) {  // quad tail, lanes past end get weight 0
    int idx = j + g;
    unsigned long long mt =
        __builtin_nontemporal_load(&meta[idx < end ? idx : end - 1]);
    float wv = (idx < end) ? pick(mt) : 0.f;
    uint4 zz = *(const uint4*)(Zb + ((unsigned)(mt & 0xffffffffu) * 256u + zlane));
    step(zz, wv);
  }
}

__global__ __launch_bounds__(256) void node_kernel(
    const unsigned short* __restrict__ Zl, const unsigned short* __restrict__ Zh,
    const unsigned short* __restrict__ Zm, const int* __restrict__ rowptr,
    const unsigned long long* __restrict__ meta, const float* __restrict__ a_low,
    const float* __restrict__ a_high, const float* __restrict__ a_mlp,
    const float* __restrict__ att_vec, float* __restrict__ out, int n_nodes) {
  int node = blockIdx.x * 4 + (threadIdx.x >> 6);
  if (node >= n_nodes) return;
  node = __builtin_amdgcn_readfirstlane(node);  // wave-uniform -> s_loads
  const int lane = threadIdx.x & 63;
  const int g = (lane >> 4) & 3;
  const int d16 = lane & 15;
  const unsigned zlane = d16 * 16;  // byte offset within 256B row

  const int start = rowptr[node];
  const int end = rowptr[node + 1];

  floatx4 hlA = (floatx4)(0.f), hlB = (floatx4)(0.f);
  floatx4 hhA = (floatx4)(0.f), hhB = (floatx4)(0.f);
  gpass((const char*)Zl, meta, start, end, g, zlane, 0, hlA, hlB);
  gpass((const char*)Zh, meta, start, end, g, zlane, 1, hhA, hhB);

  // combine the 4 edge-subgroups (same dims, different edges)
  auto red = [&](floatx4& v) {
    v.x += __shfl_xor(v.x, 16); v.x += __shfl_xor(v.x, 32);
    v.y += __shfl_xor(v.y, 16); v.y += __shfl_xor(v.y, 32);
    v.z += __shfl_xor(v.z, 16); v.z += __shfl_xor(v.z, 32);
    v.w += __shfl_xor(v.w, 16); v.w += __shfl_xor(v.w, 32);
  };
  red(hlA); red(hlB); red(hhA); red(hhB);

  // relu
  auto rl = [&](floatx4& v) {
    v.x = fmaxf(v.x, 0.f); v.y = fmaxf(v.y, 0.f);
    v.z = fmaxf(v.z, 0.f); v.w = fmaxf(v.w, 0.f);
  };
  rl(hlA); rl(hlB); rl(hhA); rl(hhB);

  // mlp branch (own node), dims d16*8..+7 — one-shot read, non-temporal
  uintx4 zm = __builtin_nontemporal_load(
      (const uintx4*)((const char*)Zm + ((unsigned)node * 256u + zlane)));
  float q0 = fmaxf(__uint_as_float(zm[0] << 16), 0.f);
  float q1 = fmaxf(__uint_as_float(zm[0] & 0xffff0000u), 0.f);
  float q2 = fmaxf(__uint_as_float(zm[1] << 16), 0.f);
  float q3 = fmaxf(__uint_as_float(zm[1] & 0xffff0000u), 0.f);
  float q4 = fmaxf(__uint_as_float(zm[2] << 16), 0.f);
  float q5 = fmaxf(__uint_as_float(zm[2] & 0xffff0000u), 0.f);
  float q6 = fmaxf(__uint_as_float(zm[3] << 16), 0.f);
  float q7 = fmaxf(__uint_as_float(zm[3] & 0xffff0000u), 0.f);

  float4 al0 = *(const float4*)&a_low[d16 * 8];
  float4 al1 = *(const float4*)&a_low[d16 * 8 + 4];
  float4 ah0 = *(const float4*)&a_high[d16 * 8];
  float4 ah1 = *(const float4*)&a_high[d16 * 8 + 4];
  float4 am0 = *(const float4*)&a_mlp[d16 * 8];
  float4 am1 = *(const float4*)&a_mlp[d16 * 8 + 4];

  float vl = hlA.x * al0.x + hlA.y * al0.y + hlA.z * al0.z + hlA.w * al0.w +
             hlB.x * al1.x + hlB.y * al1.y + hlB.z * al1.z + hlB.w * al1.w;
  float vh = hhA.x * ah0.x + hhA.y * ah0.y + hhA.z * ah0.z + hhA.w * ah0.w +
             hhB.x * ah1.x + hhB.y * ah1.y + hhB.z * ah1.z + hhB.w * ah1.w;
  float vm = q0 * am0.x + q1 * am0.y + q2 * am0.z + q3 * am0.w +
             q4 * am1.x + q5 * am1.y + q6 * am1.z + q7 * am1.w;
#pragma unroll
  for (int off = 1; off < 16; off <<= 1) {  // all lanes end with full dots
    vl += __shfl_xor(vl, off);
    vh += __shfl_xor(vh, off);
    vm += __shfl_xor(vm, off);
  }

  float g0 = 1.f / (1.f + __expf(-vl));
  float g1 = 1.f / (1.f + __expf(-vh));
  float g2 = 1.f / (1.f + __expf(-vm));
  const float inv3 = 1.f / 3.f;
  float m0 = (g0 * att_vec[0] + g1 * att_vec[3] + g2 * att_vec[6]) * inv3;
  float m1 = (g0 * att_vec[1] + g1 * att_vec[4] + g2 * att_vec[7]) * inv3;
  float m2 = (g0 * att_vec[2] + g1 * att_vec[5] + g2 * att_vec[8]) * inv3;
  float mx = fmaxf(m0, fmaxf(m1, m2));
  float e0 = __expf(m0 - mx), e1 = __expf(m1 - mx), e2 = __expf(m2 - mx);
  float inv = 1.f / (e0 + e1 + e2);
  float c0 = 3.f * inv * e0, c1 = 3.f * inv * e1, c2 = 3.f * inv * e2;

  if (g == 0) {  // lanes 0-15 write the full 512B row
    floatx4 o0, o1;
    o0.x = c0 * hlA.x + c1 * hhA.x + c2 * q0;
    o0.y = c0 * hlA.y + c1 * hhA.y + c2 * q1;
    o0.z = c0 * hlA.z + c1 * hhA.z + c2 * q2;
    o0.w = c0 * hlA.w + c1 * hhA.w + c2 * q3;
    o1.x = c0 * hlB.x + c1 * hhB.x + c2 * q4;
    o1.y = c0 * hlB.y + c1 * hhB.y + c2 * q5;
    o1.z = c0 * hlB.z + c1 * hhB.z + c2 * q6;
    o1.w = c0 * hlB.w + c1 * hhB.w + c2 * q7;
    __builtin_nontemporal_store(o0,
                                (floatx4*)&out[(size_t)node * D_OUT + d16 * 8]);
    __builtin_nontemporal_store(
        o1, (floatx4*)&out[(size_t)node * D_OUT + d16 * 8 + 4]);
  }
}

// ---------------------------------------------------------------------------
extern "C" void kernel_launch(void* const* d_in, const int* in_sizes, int n_in,
                              void* d_out, int out_size, void* d_ws,
                              size_t ws_size, hipStream_t stream) {
  const float* x    = (const float*)d_in[0];
  const int*   esrc = (const int*)d_in[1];
  const int*   edst = (const int*)d_in[2];
  const float* wlo  = (const float*)d_in[3];
  const float* whi  = (const float*)d_in[4];
  const float* Wl   = (const float*)d_in[6];
  const float* Wh   = (const float*)d_in[7];
  const float* Wm   = (const float*)d_in[8];
  const float* alo  = (const float*)d_in[9];
  const float* ahi  = (const float*)d_in[10];
  const float* amlp = (const float*)d_in[11];
  const float* av   = (const float*)d_in[12];
  float* out = (float*)d_out;

  const int N = in_sizes[0] / D_IN;  // 100000
  const int E = in_sizes[1];         // 1600000

  char* ws = (char*)d_ws;
  size_t off = 0;
  auto carve = [&](size_t bytes) -> void* {
    void* p = ws + off;
    off = (off + bytes + 255) & ~(size_t)255;
    return p;
  };
  unsigned short* Z3    = (unsigned short*)carve((size_t)N * DZ * 2);
  unsigned short* xb    = (unsigned short*)carve((size_t)N * D_IN * 2);
  unsigned short* Bpack = (unsigned short*)carve(98304 * 2);
  int*   cnt    = (int*)carve((size_t)N * 4);
  int*   rowptr = (int*)carve((size_t)(N + 1) * 4);
  int*   rank   = (int*)carve((size_t)E * 4);
  int*   bsum   = (int*)carve(128 * 4);
  uint2* meta   = (uint2*)carve((size_t)E * 8);

  const size_t zsh = (size_t)N * 128;  // shorts per plane
  unsigned short* Zl = Z3;
  unsigned short* Zh = Z3 + zsh;
  unsigned short* Zm = Z3 + 2 * zsh;

  repack_w_kernel<<<384, 256, 0, stream>>>(Wl, Wh, Wm, Bpack);
  int n8 = in_sizes[0] / 8;
  xcvt_kernel<<<(n8 + 255) / 256, 256, 0, stream>>>(x, xb, n8);

  // CSR build (independent of gemm)
  hipMemsetAsync(cnt, 0, (size_t)N * 4, stream);
  rank_kernel<<<(E / 4 + 255) / 256, 256, 0, stream>>>(edst, cnt, rank, E);
  int nb = (N + 1023) / 1024;
  scan1_kernel<<<nb, 256, 0, stream>>>(cnt, rowptr, bsum, N);
  scan2_kernel<<<1, 128, 0, stream>>>(bsum, nb);
  scan3_kernel<<<(N + 255) / 256, 256, 0, stream>>>(rowptr, bsum, N, E);
  scatter_kernel<<<(E + 255) / 256, 256, 0, stream>>>(esrc, edst, wlo, whi,
                                                      rowptr, rank, meta, E);

  gemm_kernel<<<(N + 63) / 64, 512, 0, stream>>>(xb, Bpack, Z3, N);

  node_kernel<<<(N + 3) / 4, 256, 0, stream>>>(Zl, Zh, Zm, rowptr,
                                               (const unsigned long long*)meta,
                                               alo, ahi, amlp, av, out, N);
}

// Round 5
// 506.061 us; speedup vs baseline: 1.0344x; 1.0344x over previous
//
#include <hip/hip_runtime.h>
#include <hip/hip_bf16.h>
#include <math.h>

#define D_IN   256
#define D_OUT  128
#define DZ     384   // [low | high | mlp] bf16, 768 B per row
#define NSHARD 8

typedef __attribute__((ext_vector_type(8))) short short8;
typedef __attribute__((ext_vector_type(4))) float floatx4;

__device__ __forceinline__ unsigned short f2bf(float f) {
  union { float f; unsigned u; } v; v.f = f;
  unsigned r = v.u + 0x7fffu + ((v.u >> 16) & 1u);  // RNE
  return (unsigned short)(r >> 16);
}

// ---------------------------------------------------------------------------
// prep: fused repack (blocks 0..383) + xcvt (blocks 384..).
// repack: pack [Wl|Wh|Wm] into MFMA B-fragment order.
//   frag f = kt*24+nt holds B[k=kt*32+quad*8+j][n=nt*16+(lane&15)]
// xcvt: x (fp32) -> xb (bf16), 8 elems/thread, 16B stores.
// ---------------------------------------------------------------------------
__global__ void prep_kernel(const float* __restrict__ Wl,
                            const float* __restrict__ Wh,
                            const float* __restrict__ Wm,
                            unsigned short* __restrict__ Bpack,
                            const float* __restrict__ x,
                            unsigned short* __restrict__ xb, int n8) {
  if (blockIdx.x < 384) {
    int t = blockIdx.x * 256 + threadIdx.x;  // 0..98303
    int j = t & 7;
    int lane = (t >> 3) & 63;
    int f = t >> 9;  // 0..191
    int nt = f % 24, kt = f / 24;
    int k = kt * 32 + (lane >> 4) * 8 + j;
    int n = nt * 16 + (lane & 15);
    const float* W = (n < 128) ? Wl : (n < 256 ? Wh : Wm);
    Bpack[t] = f2bf(W[k * D_OUT + (n & 127)]);
  } else {
    int i = (blockIdx.x - 384) * 256 + threadIdx.x;
    if (i < n8) {
      const float4* p = (const float4*)x + (size_t)i * 2;
      float4 f0 = p[0], f1 = p[1];
      short8 o;
      o[0] = (short)f2bf(f0.x); o[1] = (short)f2bf(f0.y);
      o[2] = (short)f2bf(f0.z); o[3] = (short)f2bf(f0.w);
      o[4] = (short)f2bf(f1.x); o[5] = (short)f2bf(f1.y);
      o[6] = (short)f2bf(f1.z); o[7] = (short)f2bf(f1.w);
      ((short8*)xb)[i] = o;
    }
  }
}

// ---------------------------------------------------------------------------
// K1: Z = xb @ [Wl|Wh|Wm], bf16 MFMA. 512-thr block = 8 waves over the same
// 64 rows; wave w owns ctiles w*3..w*3+2 (acc 4 strips x 3 ctiles = 48 AGPR).
// launch_bounds(512,4) -> 2 blocks/CU. A shared across 8 waves via L1;
// B (192 KB) is XCD-L2-resident. LDS-staged epilogue, 16B coalesced stores.
// (round-0 structure: best measured)
// ---------------------------------------------------------------------------
#define LDSROW 392  // shorts/row: 784 B (16B-aligned); 4-row stride = 16 mod 32
__global__ __launch_bounds__(512, 4) void gemm_kernel(
    const unsigned short* __restrict__ xb,
    const unsigned short* __restrict__ Bpack, unsigned short* __restrict__ Z,
    int n_nodes) {
  __shared__ unsigned short tile[64 * LDSROW];
  const int lane = threadIdx.x & 63;
  const int w = threadIdx.x >> 6;  // 0..7: column group (3 ctiles)
  const int rowbase = blockIdx.x * 64;
  const int m16 = lane & 15, quad = lane >> 4;

  floatx4 acc[4][3];
#pragma unroll
  for (int s = 0; s < 4; s++)
#pragma unroll
    for (int c = 0; c < 3; c++) acc[s][c] = (floatx4)(0.f);

  const short8* xr[4];
#pragma unroll
  for (int s = 0; s < 4; s++) {
    int r = rowbase + s * 16 + m16;
    if (r > n_nodes - 1) r = n_nodes - 1;  // clamp; stores are guarded
    xr[s] = (const short8*)xb + (size_t)r * 32 + quad;  // row*256/8 + quad
  }
  const short8* bp = (const short8*)Bpack + lane;

#pragma unroll
  for (int kt = 0; kt < 8; kt++) {
    short8 a[4];
#pragma unroll
    for (int s = 0; s < 4; s++) a[s] = xr[s][kt * 4];
#pragma unroll
    for (int c = 0; c < 3; c++) {
      short8 b = bp[(kt * 24 + w * 3 + c) * 64];
#pragma unroll
      for (int s = 0; s < 4; s++)
        acc[s][c] =
            __builtin_amdgcn_mfma_f32_16x16x32_bf16(a[s], b, acc[s][c], 0, 0, 0);
    }
  }

  // stage to LDS in C-layout (row = s*16+quad*4+r, col = (w*3+c)*16+m16)
#pragma unroll
  for (int s = 0; s < 4; s++)
#pragma unroll
    for (int c = 0; c < 3; c++)
#pragma unroll
      for (int r = 0; r < 4; r++)
        tile[(s * 16 + quad * 4 + r) * LDSROW + (w * 3 + c) * 16 + m16] =
            f2bf(acc[s][c][r]);
  __syncthreads();

  // coalesced store: 64 rows x 48 chunks of 16B = 3072 chunks / 512 thr
#pragma unroll
  for (int it = 0; it < 6; it++) {
    int chunk = it * 512 + threadIdx.x;
    int row = chunk / 48, col = (chunk % 48) * 8;
    int grow = rowbase + row;
    if (grow < n_nodes)
      *(short8*)(Z + (size_t)grow * DZ + col) =
          *(const short8*)&tile[row * LDSROW + col];
  }
}

// ---------------------------------------------------------------------------
// CSR build, rank-based, SHARDED counters (8 planar shards):
//   rank8   : shard = blockIdx&7 == (e>>10)&7; rank[e]=atomicAdd(&cnt8[s][d],1)
//             8x fewer atomics per cache line -> less cross-XCD serialization.
//   scan1/2 : exclusive scan of per-node totals (sum of 8 shards) -> rowptr
//   base    : rowfinal[d] = rowptr[d]+bsum[d>>10]; shbase[s][d] = running
//             shard-prefix (absolute positions); rowfinal[N]=E. (replaces scan3)
//   scatter : pos = shbase[(e>>10)&7][dst] + rank[e]
// ---------------------------------------------------------------------------
__global__ void rank8_kernel(const int* __restrict__ dst,
                             int* __restrict__ cnt8, int* __restrict__ rank,
                             int E, int n) {
  int* c = cnt8 + (size_t)(blockIdx.x & (NSHARD - 1)) * n;
  int e = (blockIdx.x * 256 + threadIdx.x) * 4;
  if (e + 3 < E) {
    int4 d = *(const int4*)&dst[e];
    int r0 = atomicAdd(&c[d.x], 1);
    int r1 = atomicAdd(&c[d.y], 1);
    int r2 = atomicAdd(&c[d.z], 1);
    int r3 = atomicAdd(&c[d.w], 1);
    *(int4*)&rank[e] = make_int4(r0, r1, r2, r3);
  } else {
    for (int k = e; k < E; k++) rank[k] = atomicAdd(&c[dst[k]], 1);
  }
}

__global__ __launch_bounds__(256) void scan1_kernel(
    const int* __restrict__ cnt8, int* __restrict__ rowptr,
    int* __restrict__ bsum, int n) {
  __shared__ int sd[256];
  int t = threadIdx.x;
  int base = blockIdx.x * 1024 + t * 4;
  int v0 = 0, v1 = 0, v2 = 0, v3 = 0;
  if (base < n) {  // n % 4 == 0 so base<n implies base+3<n
#pragma unroll
    for (int s = 0; s < NSHARD; s++) {
      int4 cc = *(const int4*)&cnt8[(size_t)s * n + base];
      v0 += cc.x; v1 += cc.y; v2 += cc.z; v3 += cc.w;
    }
  }
  int tsum = v0 + v1 + v2 + v3;
  sd[t] = tsum;
  __syncthreads();
  for (int off = 1; off < 256; off <<= 1) {
    int add = (t >= off) ? sd[t - off] : 0;
    __syncthreads();
    sd[t] += add;
    __syncthreads();
  }
  int excl = sd[t] - tsum;
  if (base + 0 < n) rowptr[base + 0] = excl;
  if (base + 1 < n) rowptr[base + 1] = excl + v0;
  if (base + 2 < n) rowptr[base + 2] = excl + v0 + v1;
  if (base + 3 < n) rowptr[base + 3] = excl + v0 + v1 + v2;
  if (t == 255) bsum[blockIdx.x] = sd[255];
}

__global__ __launch_bounds__(128) void scan2_kernel(int* __restrict__ bsum,
                                                    int nb) {
  __shared__ int sd[128];
  int t = threadIdx.x;
  int v = t < nb ? bsum[t] : 0;
  sd[t] = v;
  __syncthreads();
  for (int off = 1; off < 128; off <<= 1) {
    int add = (t >= off) ? sd[t - off] : 0;
    __syncthreads();
    sd[t] += add;
    __syncthreads();
  }
  if (t < nb) bsum[t] = sd[t] - v;  // exclusive
}

__global__ void base_kernel(const int* __restrict__ rowptr,
                            const int* __restrict__ bsum,
                            const int* __restrict__ cnt8,
                            int* __restrict__ rowfinal,
                            int* __restrict__ shbase, int n, int E) {
  int i = blockIdx.x * 256 + threadIdx.x;
  if (i < n) {
    int off = rowptr[i] + bsum[i >> 10];
    rowfinal[i] = off;
    int run = off;
#pragma unroll
    for (int s = 0; s < NSHARD; s++) {
      shbase[(size_t)s * n + i] = run;
      run += cnt8[(size_t)s * n + i];
    }
    if (i == 0) rowfinal[n] = E;
  }
}

__global__ void scatter_kernel(const int* __restrict__ src,
                               const int* __restrict__ dst,
                               const float* __restrict__ wlo,
                               const float* __restrict__ whi,
                               const int* __restrict__ shbase,
                               const int* __restrict__ rank,
                               uint2* __restrict__ meta, int E, int n) {
  int e = blockIdx.x * 256 + threadIdx.x;
  if (e < E) {
    int d = dst[e];
    int shard = (e >> 10) & (NSHARD - 1);
    int pos = shbase[(size_t)shard * n + d] + rank[e];
    unsigned wl = f2bf(wlo[e]), wh = f2bf(whi[e]);
    meta[pos] = make_uint2((unsigned)src[e], wl | (wh << 16));
  }
}

// ---------------------------------------------------------------------------
// K_node: CSR gather + relu + attention3. 128-thr blocks = 2 independent
// waves = 2 nodes. readfirstlane(node) -> rowptr/meta via scalar loads.
// Lane l<32: low dims 4l..4l+3; l>=32: high dims. One uint2 Z load per edge,
// unroll x8. (round-0 structure: best measured at 122.6us)
// ---------------------------------------------------------------------------
__global__ __launch_bounds__(128) void node_kernel(
    const unsigned short* __restrict__ Zh, const int* __restrict__ rowptr,
    const uint2* __restrict__ meta, const float* __restrict__ a_low,
    const float* __restrict__ a_high, const float* __restrict__ a_mlp,
    const float* __restrict__ att_vec, float* __restrict__ out, int n_nodes) {
  int node = blockIdx.x * 2 + (threadIdx.x >> 6);
  if (node >= n_nodes) return;
  node = __builtin_amdgcn_readfirstlane(node);  // wave-uniform -> s_loads
  const int lane = threadIdx.x & 63;
  const int isHigh = lane >> 5;
  const int dbase = (lane & 31) * 4;
  const char* Zb = (const char*)Zh;

  const int start = rowptr[node];
  const int end = rowptr[node + 1];

  float acc0 = 0.f, acc1 = 0.f, acc2 = 0.f, acc3 = 0.f;
  auto wsel = [&](unsigned p) {
    return __uint_as_float(isHigh ? (p & 0xffff0000u) : (p << 16));
  };
  auto step = [&](uint2 z, float wv) {
    acc0 += wv * __uint_as_float(z.x << 16);
    acc1 += wv * __uint_as_float(z.x & 0xffff0000u);
    acc2 += wv * __uint_as_float(z.y << 16);
    acc3 += wv * __uint_as_float(z.y & 0xffff0000u);
  };

  int j = start;
  const int nfull = (end - start) & ~7;
  for (; j < start + nfull; j += 8) {
    uint2 m[8], z[8];
#pragma unroll
    for (int u = 0; u < 8; u++) m[u] = meta[j + u];
#pragma unroll
    for (int u = 0; u < 8; u++)
      z[u] = *(const uint2*)(Zb + (size_t)m[u].x * 768 + lane * 8);
#pragma unroll
    for (int u = 0; u < 8; u++) step(z[u], wsel(m[u].y));
  }
  for (; j < end; j++) {
    uint2 m0 = meta[j];
    uint2 z0 = *(const uint2*)(Zb + (size_t)m0.x * 768 + lane * 8);
    step(z0, wsel(m0.y));
  }

  float h0 = fmaxf(acc0, 0.f), h1 = fmaxf(acc1, 0.f);
  float h2 = fmaxf(acc2, 0.f), h3 = fmaxf(acc3, 0.f);

  uint2 zm =
      *(const uint2*)(Zb + (size_t)node * 768 + 512 + (size_t)(lane & 31) * 8);
  float q0 = fmaxf(__uint_as_float(zm.x << 16), 0.f);
  float q1 = fmaxf(__uint_as_float(zm.x & 0xffff0000u), 0.f);
  float q2 = fmaxf(__uint_as_float(zm.y << 16), 0.f);
  float q3 = fmaxf(__uint_as_float(zm.y & 0xffff0000u), 0.f);

  const float* av_b = isHigh ? a_high : a_low;
  float4 ab = *(const float4*)&av_b[dbase];
  float4 am = *(const float4*)&a_mlp[dbase];
  float v1 = h0 * ab.x + h1 * ab.y + h2 * ab.z + h3 * ab.w;
  float v2 = isHigh ? 0.f : (q0 * am.x + q1 * am.y + q2 * am.z + q3 * am.w);
#pragma unroll
  for (int off = 1; off < 32; off <<= 1) {
    v1 += __shfl_xor(v1, off);
    v2 += __shfl_xor(v2, off);
  }
  float s_lo = __shfl(v1, 0);
  float s_hi = __shfl(v1, 32);
  float s_ml = __shfl(v2, 0);

  float g0 = 1.f / (1.f + __expf(-s_lo));
  float g1 = 1.f / (1.f + __expf(-s_hi));
  float g2 = 1.f / (1.f + __expf(-s_ml));
  const float inv3 = 1.f / 3.f;
  float m0 = (g0 * att_vec[0] + g1 * att_vec[3] + g2 * att_vec[6]) * inv3;
  float m1 = (g0 * att_vec[1] + g1 * att_vec[4] + g2 * att_vec[7]) * inv3;
  float m2 = (g0 * att_vec[2] + g1 * att_vec[5] + g2 * att_vec[8]) * inv3;
  float mx = fmaxf(m0, fmaxf(m1, m2));
  float e0 = __expf(m0 - mx), e1 = __expf(m1 - mx), e2 = __expf(m2 - mx);
  float inv = 1.f / (e0 + e1 + e2);
  float c0 = 3.f * inv * e0, c1 = 3.f * inv * e1, c2 = 3.f * inv * e2;

  float hh0 = __shfl_xor(h0, 32);
  float hh1 = __shfl_xor(h1, 32);
  float hh2 = __shfl_xor(h2, 32);
  float hh3 = __shfl_xor(h3, 32);

  if (!isHigh) {
    float4 o;
    o.x = c0 * h0 + c1 * hh0 + c2 * q0;
    o.y = c0 * h1 + c1 * hh1 + c2 * q1;
    o.z = c0 * h2 + c1 * hh2 + c2 * q2;
    o.w = c0 * h3 + c1 * hh3 + c2 * q3;
    *(float4*)&out[(size_t)node * D_OUT + dbase] = o;
  }
}

// ---------------------------------------------------------------------------
extern "C" void kernel_launch(void* const* d_in, const int* in_sizes, int n_in,
                              void* d_out, int out_size, void* d_ws,
                              size_t ws_size, hipStream_t stream) {
  const float* x    = (const float*)d_in[0];
  const int*   esrc = (const int*)d_in[1];
  const int*   edst = (const int*)d_in[2];
  const float* wlo  = (const float*)d_in[3];
  const float* whi  = (const float*)d_in[4];
  const float* Wl   = (const float*)d_in[6];
  const float* Wh   = (const float*)d_in[7];
  const float* Wm   = (const float*)d_in[8];
  const float* alo  = (const float*)d_in[9];
  const float* ahi  = (const float*)d_in[10];
  const float* amlp = (const float*)d_in[11];
  const float* av   = (const float*)d_in[12];
  float* out = (float*)d_out;

  const int N = in_sizes[0] / D_IN;  // 100000
  const int E = in_sizes[1];         // 1600000

  char* ws = (char*)d_ws;
  size_t off = 0;
  auto carve = [&](size_t bytes) -> void* {
    void* p = ws + off;
    off = (off + bytes + 255) & ~(size_t)255;
    return p;
  };
  unsigned short* Z     = (unsigned short*)carve((size_t)N * DZ * 2);
  unsigned short* xb    = (unsigned short*)carve((size_t)N * D_IN * 2);
  unsigned short* Bpack = (unsigned short*)carve(98304 * 2);
  int*   cnt8   = (int*)carve((size_t)NSHARD * N * 4);
  int*   rowptr = (int*)carve((size_t)(N + 1) * 4);
  int*   rowfin = (int*)carve((size_t)(N + 1) * 4);
  int*   shbase = (int*)carve((size_t)NSHARD * N * 4);
  int*   rank   = (int*)carve((size_t)E * 4);
  int*   bsum   = (int*)carve(128 * 4);
  uint2* meta   = (uint2*)carve((size_t)E * 8);

  int n8 = in_sizes[0] / 8;
  prep_kernel<<<384 + (n8 + 255) / 256, 256, 0, stream>>>(Wl, Wh, Wm, Bpack, x,
                                                          xb, n8);

  // CSR build (independent of gemm)
  hipMemsetAsync(cnt8, 0, (size_t)NSHARD * N * 4, stream);
  rank8_kernel<<<(E / 4 + 255) / 256, 256, 0, stream>>>(edst, cnt8, rank, E, N);
  int nb = (N + 1023) / 1024;
  scan1_kernel<<<nb, 256, 0, stream>>>(cnt8, rowptr, bsum, N);
  scan2_kernel<<<1, 128, 0, stream>>>(bsum, nb);
  base_kernel<<<(N + 255) / 256, 256, 0, stream>>>(rowptr, bsum, cnt8, rowfin,
                                                   shbase, N, E);
  scatter_kernel<<<(E + 255) / 256, 256, 0, stream>>>(esrc, edst, wlo, whi,
                                                      shbase, rank, meta, E, N);

  gemm_kernel<<<(N + 63) / 64, 512, 0, stream>>>(xb, Bpack, Z, N);

  node_kernel<<<(N + 1) / 2, 128, 0, stream>>>(Z, rowfin, meta, alo, ahi, amlp,
                                               av, out, N);
}

// Round 6
// 468.714 us; speedup vs baseline: 1.1168x; 1.0797x over previous
//
#include <hip/hip_runtime.h>
#include <hip/hip_bf16.h>
#include <math.h>

#define D_IN   256
#define D_OUT  128
#define DZ     384   // [low | high | mlp] bf16, 768 B per row

typedef __attribute__((ext_vector_type(8))) short short8;
typedef __attribute__((ext_vector_type(4))) float floatx4;

__device__ __forceinline__ unsigned short f2bf(float f) {
  union { float f; unsigned u; } v; v.f = f;
  unsigned r = v.u + 0x7fffu + ((v.u >> 16) & 1u);  // RNE
  return (unsigned short)(r >> 16);
}

// ---------------------------------------------------------------------------
// prep: fused repack + xcvt + cnt-zeroing (three block ranges).
// repack: pack [Wl|Wh|Wm] into MFMA B-fragment order.
//   frag f = kt*24+nt holds B[k=kt*32+quad*8+j][n=nt*16+(lane&15)]
// xcvt: x (fp32) -> xb (bf16), 8 elems/thread, 16B stores.
// zero: cnt[0..n) = 0 (replaces hipMemsetAsync launch).
// ---------------------------------------------------------------------------
__global__ void prep_kernel(const float* __restrict__ Wl,
                            const float* __restrict__ Wh,
                            const float* __restrict__ Wm,
                            unsigned short* __restrict__ Bpack,
                            const float* __restrict__ x,
                            unsigned short* __restrict__ xb, int n8,
                            int* __restrict__ cnt, int n, int nxb) {
  int bid = blockIdx.x;
  if (bid < 384) {
    int t = bid * 256 + threadIdx.x;  // 0..98303
    int j = t & 7;
    int lane = (t >> 3) & 63;
    int f = t >> 9;  // 0..191
    int nt = f % 24, kt = f / 24;
    int k = kt * 32 + (lane >> 4) * 8 + j;
    int n_ = nt * 16 + (lane & 15);
    const float* W = (n_ < 128) ? Wl : (n_ < 256 ? Wh : Wm);
    Bpack[t] = f2bf(W[k * D_OUT + (n_ & 127)]);
  } else if (bid < 384 + nxb) {
    int i = (bid - 384) * 256 + threadIdx.x;
    if (i < n8) {
      const float4* p = (const float4*)x + (size_t)i * 2;
      float4 f0 = p[0], f1 = p[1];
      short8 o;
      o[0] = (short)f2bf(f0.x); o[1] = (short)f2bf(f0.y);
      o[2] = (short)f2bf(f0.z); o[3] = (short)f2bf(f0.w);
      o[4] = (short)f2bf(f1.x); o[5] = (short)f2bf(f1.y);
      o[6] = (short)f2bf(f1.z); o[7] = (short)f2bf(f1.w);
      ((short8*)xb)[i] = o;
    }
  } else {
    int i = (bid - 384 - nxb) * 1024 + threadIdx.x * 4;
    if (i < n) *(int4*)&cnt[i] = make_int4(0, 0, 0, 0);  // n % 4 == 0
  }
}

// ---------------------------------------------------------------------------
// FUSED gemm + rank. rank (latency-bound random atomics, ~150us) and gemm
// (MFMA-bound, ~100us) are independent; interleaving their blocks in one
// launch co-schedules them on the CUs (time ~ max, not sum — m114 overlap).
// Even block ids (first 2*nrank) = rank chunks; odd = gemm tiles; remainder
// = gemm. rank blocks dispatch early so their atomic latency hides under
// the MFMA stream.
//
// gemm part: Z = xb @ [Wl|Wh|Wm], bf16 MFMA. 512-thr block = 8 waves over
// the same 64 rows; wave w owns ctiles w*3..w*3+2 (48 AGPR acc). A shared
// across 8 waves via L1; B (192 KB) XCD-L2-resident. LDS epilogue, 16B
// coalesced stores. (round-0 structure: best measured)
// rank part: rank[e] = atomicAdd(&cnt[dst[e]],1), 4 edges/thread.
// ---------------------------------------------------------------------------
#define LDSROW 392  // shorts/row: 784 B (16B-aligned); 4-row stride = 16 mod 32
__global__ __launch_bounds__(512, 4) void gemm_rank_kernel(
    const unsigned short* __restrict__ xb,
    const unsigned short* __restrict__ Bpack, unsigned short* __restrict__ Z,
    int n_nodes, const int* __restrict__ dst, int* __restrict__ cnt,
    int* __restrict__ rank, int E, int nrank) {
  __shared__ unsigned short tile[64 * LDSROW];
  const int bid = blockIdx.x;

  int gemm_id;
  if (bid < 2 * nrank) {
    if ((bid & 1) == 0) {  // ---- rank block ----
      int rb = bid >> 1;
      int e = (rb * 512 + threadIdx.x) * 4;
      if (e + 3 < E) {
        int4 d = *(const int4*)&dst[e];
        int r0 = atomicAdd(&cnt[d.x], 1);
        int r1 = atomicAdd(&cnt[d.y], 1);
        int r2 = atomicAdd(&cnt[d.z], 1);
        int r3 = atomicAdd(&cnt[d.w], 1);
        *(int4*)&rank[e] = make_int4(r0, r1, r2, r3);
      } else {
        for (int k = e; k < E; k++) rank[k] = atomicAdd(&cnt[dst[k]], 1);
      }
      return;
    }
    gemm_id = bid >> 1;
  } else {
    gemm_id = (bid - 2 * nrank) + nrank;
  }

  // ---- gemm block ----
  const int lane = threadIdx.x & 63;
  const int w = threadIdx.x >> 6;  // 0..7: column group (3 ctiles)
  const int rowbase = gemm_id * 64;
  const int m16 = lane & 15, quad = lane >> 4;

  floatx4 acc[4][3];
#pragma unroll
  for (int s = 0; s < 4; s++)
#pragma unroll
    for (int c = 0; c < 3; c++) acc[s][c] = (floatx4)(0.f);

  const short8* xr[4];
#pragma unroll
  for (int s = 0; s < 4; s++) {
    int r = rowbase + s * 16 + m16;
    if (r > n_nodes - 1) r = n_nodes - 1;  // clamp; stores are guarded
    xr[s] = (const short8*)xb + (size_t)r * 32 + quad;  // row*256/8 + quad
  }
  const short8* bp = (const short8*)Bpack + lane;

#pragma unroll
  for (int kt = 0; kt < 8; kt++) {
    short8 a[4];
#pragma unroll
    for (int s = 0; s < 4; s++) a[s] = xr[s][kt * 4];
#pragma unroll
    for (int c = 0; c < 3; c++) {
      short8 b = bp[(kt * 24 + w * 3 + c) * 64];
#pragma unroll
      for (int s = 0; s < 4; s++)
        acc[s][c] =
            __builtin_amdgcn_mfma_f32_16x16x32_bf16(a[s], b, acc[s][c], 0, 0, 0);
    }
  }

  // stage to LDS in C-layout (row = s*16+quad*4+r, col = (w*3+c)*16+m16)
#pragma unroll
  for (int s = 0; s < 4; s++)
#pragma unroll
    for (int c = 0; c < 3; c++)
#pragma unroll
      for (int r = 0; r < 4; r++)
        tile[(s * 16 + quad * 4 + r) * LDSROW + (w * 3 + c) * 16 + m16] =
            f2bf(acc[s][c][r]);
  __syncthreads();

  // coalesced store: 64 rows x 48 chunks of 16B = 3072 chunks / 512 thr
#pragma unroll
  for (int it = 0; it < 6; it++) {
    int chunk = it * 512 + threadIdx.x;
    int row = chunk / 48, col = (chunk % 48) * 8;
    int grow = rowbase + row;
    if (grow < n_nodes)
      *(short8*)(Z + (size_t)grow * DZ + col) =
          *(const short8*)&tile[row * LDSROW + col];
  }
}

// ---------------------------------------------------------------------------
// CSR build tail: scan of cnt -> rowptr, then scatter.
// ---------------------------------------------------------------------------
__global__ __launch_bounds__(256) void scan1_kernel(
    const int* __restrict__ cnt, int* __restrict__ rowptr,
    int* __restrict__ bsum, int n) {
  __shared__ int sd[256];
  int t = threadIdx.x;
  int base = blockIdx.x * 1024 + t * 4;
  int v0 = base + 0 < n ? cnt[base + 0] : 0;
  int v1 = base + 1 < n ? cnt[base + 1] : 0;
  int v2 = base + 2 < n ? cnt[base + 2] : 0;
  int v3 = base + 3 < n ? cnt[base + 3] : 0;
  int tsum = v0 + v1 + v2 + v3;
  sd[t] = tsum;
  __syncthreads();
  for (int off = 1; off < 256; off <<= 1) {
    int add = (t >= off) ? sd[t - off] : 0;
    __syncthreads();
    sd[t] += add;
    __syncthreads();
  }
  int excl = sd[t] - tsum;
  if (base + 0 < n) rowptr[base + 0] = excl;
  if (base + 1 < n) rowptr[base + 1] = excl + v0;
  if (base + 2 < n) rowptr[base + 2] = excl + v0 + v1;
  if (base + 3 < n) rowptr[base + 3] = excl + v0 + v1 + v2;
  if (t == 255) bsum[blockIdx.x] = sd[255];
}

__global__ __launch_bounds__(128) void scan2_kernel(int* __restrict__ bsum,
                                                    int nb) {
  __shared__ int sd[128];
  int t = threadIdx.x;
  int v = t < nb ? bsum[t] : 0;
  sd[t] = v;
  __syncthreads();
  for (int off = 1; off < 128; off <<= 1) {
    int add = (t >= off) ? sd[t - off] : 0;
    __syncthreads();
    sd[t] += add;
    __syncthreads();
  }
  if (t < nb) bsum[t] = sd[t] - v;  // exclusive
}

__global__ void scan3_kernel(int* __restrict__ rowptr,
                             const int* __restrict__ bsum, int n, int E) {
  int i = blockIdx.x * 256 + threadIdx.x;
  if (i < n) {
    rowptr[i] = rowptr[i] + bsum[i >> 10];
    if (i == 0) rowptr[n] = E;
  }
}

__global__ void scatter_kernel(const int* __restrict__ src,
                               const int* __restrict__ dst,
                               const float* __restrict__ wlo,
                               const float* __restrict__ whi,
                               const int* __restrict__ rowptr,
                               const int* __restrict__ rank,
                               uint2* __restrict__ meta, int E) {
  int e = blockIdx.x * 256 + threadIdx.x;
  if (e < E) {
    int d = dst[e];
    int pos = rowptr[d] + rank[e];
    unsigned wl = f2bf(wlo[e]), wh = f2bf(whi[e]);
    meta[pos] = make_uint2((unsigned)src[e], wl | (wh << 16));
  }
}

// ---------------------------------------------------------------------------
// K_node: CSR gather + relu + attention3. 128-thr blocks = 2 independent
// waves = 2 nodes. readfirstlane(node) -> rowptr/meta via scalar loads.
// Lane l<32: low dims 4l..4l+3; l>=32: high dims. One uint2 Z load per edge,
// unroll x8. (round-0 structure: best measured at 122.6us)
// ---------------------------------------------------------------------------
__global__ __launch_bounds__(128) void node_kernel(
    const unsigned short* __restrict__ Zh, const int* __restrict__ rowptr,
    const uint2* __restrict__ meta, const float* __restrict__ a_low,
    const float* __restrict__ a_high, const float* __restrict__ a_mlp,
    const float* __restrict__ att_vec, float* __restrict__ out, int n_nodes) {
  int node = blockIdx.x * 2 + (threadIdx.x >> 6);
  if (node >= n_nodes) return;
  node = __builtin_amdgcn_readfirstlane(node);  // wave-uniform -> s_loads
  const int lane = threadIdx.x & 63;
  const int isHigh = lane >> 5;
  const int dbase = (lane & 31) * 4;
  const char* Zb = (const char*)Zh;

  const int start = rowptr[node];
  const int end = rowptr[node + 1];

  float acc0 = 0.f, acc1 = 0.f, acc2 = 0.f, acc3 = 0.f;
  auto wsel = [&](unsigned p) {
    return __uint_as_float(isHigh ? (p & 0xffff0000u) : (p << 16));
  };
  auto step = [&](uint2 z, float wv) {
    acc0 += wv * __uint_as_float(z.x << 16);
    acc1 += wv * __uint_as_float(z.x & 0xffff0000u);
    acc2 += wv * __uint_as_float(z.y << 16);
    acc3 += wv * __uint_as_float(z.y & 0xffff0000u);
  };

  int j = start;
  const int nfull = (end - start) & ~7;
  for (; j < start + nfull; j += 8) {
    uint2 m[8], z[8];
#pragma unroll
    for (int u = 0; u < 8; u++) m[u] = meta[j + u];
#pragma unroll
    for (int u = 0; u < 8; u++)
      z[u] = *(const uint2*)(Zb + (size_t)m[u].x * 768 + lane * 8);
#pragma unroll
    for (int u = 0; u < 8; u++) step(z[u], wsel(m[u].y));
  }
  for (; j < end; j++) {
    uint2 m0 = meta[j];
    uint2 z0 = *(const uint2*)(Zb + (size_t)m0.x * 768 + lane * 8);
    step(z0, wsel(m0.y));
  }

  float h0 = fmaxf(acc0, 0.f), h1 = fmaxf(acc1, 0.f);
  float h2 = fmaxf(acc2, 0.f), h3 = fmaxf(acc3, 0.f);

  uint2 zm =
      *(const uint2*)(Zb + (size_t)node * 768 + 512 + (size_t)(lane & 31) * 8);
  float q0 = fmaxf(__uint_as_float(zm.x << 16), 0.f);
  float q1 = fmaxf(__uint_as_float(zm.x & 0xffff0000u), 0.f);
  float q2 = fmaxf(__uint_as_float(zm.y << 16), 0.f);
  float q3 = fmaxf(__uint_as_float(zm.y & 0xffff0000u), 0.f);

  const float* av_b = isHigh ? a_high : a_low;
  float4 ab = *(const float4*)&av_b[dbase];
  float4 am = *(const float4*)&a_mlp[dbase];
  float v1 = h0 * ab.x + h1 * ab.y + h2 * ab.z + h3 * ab.w;
  float v2 = isHigh ? 0.f : (q0 * am.x + q1 * am.y + q2 * am.z + q3 * am.w);
#pragma unroll
  for (int off = 1; off < 32; off <<= 1) {
    v1 += __shfl_xor(v1, off);
    v2 += __shfl_xor(v2, off);
  }
  float s_lo = __shfl(v1, 0);
  float s_hi = __shfl(v1, 32);
  float s_ml = __shfl(v2, 0);

  float g0 = 1.f / (1.f + __expf(-s_lo));
  float g1 = 1.f / (1.f + __expf(-s_hi));
  float g2 = 1.f / (1.f + __expf(-s_ml));
  const float inv3 = 1.f / 3.f;
  float m0 = (g0 * att_vec[0] + g1 * att_vec[3] + g2 * att_vec[6]) * inv3;
  float m1 = (g0 * att_vec[1] + g1 * att_vec[4] + g2 * att_vec[7]) * inv3;
  float m2 = (g0 * att_vec[2] + g1 * att_vec[5] + g2 * att_vec[8]) * inv3;
  float mx = fmaxf(m0, fmaxf(m1, m2));
  float e0 = __expf(m0 - mx), e1 = __expf(m1 - mx), e2 = __expf(m2 - mx);
  float inv = 1.f / (e0 + e1 + e2);
  float c0 = 3.f * inv * e0, c1 = 3.f * inv * e1, c2 = 3.f * inv * e2;

  float hh0 = __shfl_xor(h0, 32);
  float hh1 = __shfl_xor(h1, 32);
  float hh2 = __shfl_xor(h2, 32);
  float hh3 = __shfl_xor(h3, 32);

  if (!isHigh) {
    float4 o;
    o.x = c0 * h0 + c1 * hh0 + c2 * q0;
    o.y = c0 * h1 + c1 * hh1 + c2 * q1;
    o.z = c0 * h2 + c1 * hh2 + c2 * q2;
    o.w = c0 * h3 + c1 * hh3 + c2 * q3;
    *(float4*)&out[(size_t)node * D_OUT + dbase] = o;
  }
}

// ---------------------------------------------------------------------------
extern "C" void kernel_launch(void* const* d_in, const int* in_sizes, int n_in,
                              void* d_out, int out_size, void* d_ws,
                              size_t ws_size, hipStream_t stream) {
  const float* x    = (const float*)d_in[0];
  const int*   esrc = (const int*)d_in[1];
  const int*   edst = (const int*)d_in[2];
  const float* wlo  = (const float*)d_in[3];
  const float* whi  = (const float*)d_in[4];
  const float* Wl   = (const float*)d_in[6];
  const float* Wh   = (const float*)d_in[7];
  const float* Wm   = (const float*)d_in[8];
  const float* alo  = (const float*)d_in[9];
  const float* ahi  = (const float*)d_in[10];
  const float* amlp = (const float*)d_in[11];
  const float* av   = (const float*)d_in[12];
  float* out = (float*)d_out;

  const int N = in_sizes[0] / D_IN;  // 100000
  const int E = in_sizes[1];         // 1600000

  char* ws = (char*)d_ws;
  size_t off = 0;
  auto carve = [&](size_t bytes) -> void* {
    void* p = ws + off;
    off = (off + bytes + 255) & ~(size_t)255;
    return p;
  };
  unsigned short* Z     = (unsigned short*)carve((size_t)N * DZ * 2);
  unsigned short* xb    = (unsigned short*)carve((size_t)N * D_IN * 2);
  unsigned short* Bpack = (unsigned short*)carve(98304 * 2);
  int*   cnt    = (int*)carve((size_t)N * 4);
  int*   rowptr = (int*)carve((size_t)(N + 1) * 4);
  int*   rank   = (int*)carve((size_t)E * 4);
  int*   bsum   = (int*)carve(128 * 4);
  uint2* meta   = (uint2*)carve((size_t)E * 8);

  int n8 = in_sizes[0] / 8;
  int nxb = (n8 + 255) / 256;
  int nzb = (N + 1023) / 1024;
  prep_kernel<<<384 + nxb + nzb, 256, 0, stream>>>(Wl, Wh, Wm, Bpack, x, xb, n8,
                                                   cnt, N, nxb);

  // fused gemm + rank (independent work, co-scheduled)
  int ngemm = (N + 63) / 64;
  int nrank = (E + 2047) / 2048;
  gemm_rank_kernel<<<ngemm + nrank, 512, 0, stream>>>(xb, Bpack, Z, N, edst,
                                                      cnt, rank, E, nrank);

  int nb = (N + 1023) / 1024;
  scan1_kernel<<<nb, 256, 0, stream>>>(cnt, rowptr, bsum, N);
  scan2_kernel<<<1, 128, 0, stream>>>(bsum, nb);
  scan3_kernel<<<(N + 255) / 256, 256, 0, stream>>>(rowptr, bsum, N, E);
  scatter_kernel<<<(E + 255) / 256, 256, 0, stream>>>(esrc, edst, wlo, whi,
                                                      rowptr, rank, meta, E);

  node_kernel<<<(N + 1) / 2, 128, 0, stream>>>(Z, rowptr, meta, alo, ahi, amlp,
                                               av, out, N);
}